// Round 14
// baseline (596.452 us; speedup 1.0000x reference)
//
#include <hip/hip_runtime.h>

// Bit-exact emulation of segmented sparsemax with cumsum lowered like XLA's
// ReduceWindowRewriter (base 16). GREEN since R7 (absmax 0.0).
// R14: tail collapsed into ONE persistent kernel (kTAIL, 1024 blocks, 4 spin
// barriers; co-residency margin 2x) -> 3 launches total. k2w sort unchanged
// from R13. All scan arithmetic keeps the exact association order.

#define NSEG   8192
#define NTOT   8388608   // 2^23
#define L1N    524288    // 2^19
#define L2N    32768     // 2^15
#define L3N    2048
#define PADV   (-3.0e38f)
#define WREG   1552      // per-wave LDS floats (1536 + 16 pad)
#define NTB    1024      // kTAIL blocks (co-resident: capacity ~2048)
#define SEGB   (NSEG / NTB)   // 8 segments per kTAIL block
#define FBB    256

// element -> physical LDS slot: rotate column by row (spreads banks)
__device__ __forceinline__ int esw(const int e) {
    return (e & ~15) | ((e + (e >> 4)) & 15);
}

__device__ __forceinline__ void cs(float& a, float& b, const bool up) {
    const float lo = fminf(a, b), hi = fmaxf(a, b);
    a = up ? hi : lo;
    b = up ? lo : hi;
}

// ---- 8-reg (512-elem) wave sort pieces (verified since R9) ----
__device__ __forceinline__ void sort8(float r[8], const int gib) {
    cs(r[0], r[1], true);  cs(r[2], r[3], false); cs(r[4], r[5], true);  cs(r[6], r[7], false);
    cs(r[0], r[2], true);  cs(r[1], r[3], true);  cs(r[4], r[6], false); cs(r[5], r[7], false);
    cs(r[0], r[1], true);  cs(r[2], r[3], true);  cs(r[4], r[5], false); cs(r[6], r[7], false);
    const bool u8 = ((gib & 8) == 0);
    cs(r[0], r[4], u8); cs(r[1], r[5], u8); cs(r[2], r[6], u8); cs(r[3], r[7], u8);
    cs(r[0], r[2], u8); cs(r[1], r[3], u8); cs(r[4], r[6], u8); cs(r[5], r[7], u8);
    cs(r[0], r[1], u8); cs(r[2], r[3], u8); cs(r[4], r[5], u8); cs(r[6], r[7], u8);
}

template<int K>
__device__ __forceinline__ void bmerge(float r[8], const int gib) {
    const bool up = ((gib & K) == 0);
    #pragma unroll
    for (int j = K >> 1; j >= 8; j >>= 1) {
        const bool tkm = (up == ((gib & j) == 0));
        const int tm = j >> 3;
        #pragma unroll
        for (int m = 0; m < 8; ++m) {
            const float p = __shfl_xor(r[m], tm, 64);
            r[m] = tkm ? fmaxf(r[m], p) : fminf(r[m], p);
        }
    }
    #pragma unroll
    for (int j = 4; j >= 1; j >>= 1)
        #pragma unroll
        for (int m = 0; m < 8; ++m)
            if ((m & j) == 0) cs(r[m], r[m | j], up);
}

// ---- 16-reg (1024-elem) wave sort ----
template<int K, int J>
__device__ __forceinline__ void cepm(float r[16]) {
    #pragma unroll
    for (int m = 0; m < 16; ++m)
        if ((m & J) == 0) { const bool up = ((m & K) == 0); cs(r[m], r[m | J], up); }
}
template<int J>
__device__ __forceinline__ void cep(float r[16], const bool up) {
    #pragma unroll
    for (int m = 0; m < 16; ++m)
        if ((m & J) == 0) cs(r[m], r[m | J], up);
}
template<int KD>
__device__ __forceinline__ void kphase16(float r[16], const int l) {
    const bool up = ((l & (KD >> 4)) == 0);
    #pragma unroll
    for (int tm = KD >> 5; tm >= 1; tm >>= 1) {
        const bool tkm = (up == ((l & tm) == 0));
        #pragma unroll
        for (int m = 0; m < 16; ++m) {
            const float p = __shfl_xor(r[m], tm, 64);
            r[m] = tkm ? fmaxf(r[m], p) : fminf(r[m], p);
        }
    }
    cep<8>(r, up); cep<4>(r, up); cep<2>(r, up); cep<1>(r, up);
}
__device__ __forceinline__ void wsort1024(float r[16], const int l) {
    cepm<2, 1>(r);
    cepm<4, 2>(r); cepm<4, 1>(r);
    cepm<8, 4>(r); cepm<8, 2>(r); cepm<8, 1>(r);
    kphase16<16>(r, l);  kphase16<32>(r, l);  kphase16<64>(r, l);
    kphase16<128>(r, l); kphase16<256>(r, l); kphase16<512>(r, l);
    kphase16<1024>(r, l);
}

__global__ void k1_bounds(const int* __restrict__ batch, int* __restrict__ starts,
                          int* __restrict__ ctrs, const int n)
{
    const int i = blockIdx.x * blockDim.x + threadIdx.x;
    if (blockIdx.x == 0 && threadIdx.x < 8) ctrs[threadIdx.x] = 0;   // re-zero every replay
    if (i >= n) return;
    const int bi = batch[i];
    if (i == 0) { for (int b = 0; b <= bi; ++b) starts[b] = 0; }
    else {
        const int bp = batch[i - 1];
        for (int b = bp + 1; b <= bi; ++b) starts[b] = i;
    }
    if (i == n - 1) { for (int b = bi + 1; b <= NSEG; ++b) starts[b] = n; }
}

// -------- k2w: one WAVE per segment; no __syncthreads (unchanged from R13) --------
__global__ __launch_bounds__(256) void k2w(
    const float* __restrict__ x, const int* __restrict__ starts,
    float* __restrict__ mx_out, float* __restrict__ S, float* __restrict__ L1)
{
    __shared__ __align__(16) float Wall[4 * WREG];
    const int tid  = threadIdx.x;
    const int lane = tid & 63;
    const int wid  = tid >> 6;
    float* W = Wall + wid * WREG;

    const int b = blockIdx.x * 4 + wid;
    const int s = starts[b], e = starts[b + 1];
    const int n = e - s;
    if (n <= 0) { if (lane == 0) mx_out[b] = 0.0f; return; }

    const bool med = (n > 1024);
    const int  nb  = n - 1024;

    float r[16], rb[8];
    #pragma unroll
    for (int m = 0; m < 16; ++m) { const int i = 16 * lane + m; r[m] = (i < n) ? x[s + i] : PADV; }
    if (med) {
        #pragma unroll
        for (int m = 0; m < 8; ++m) { const int i = 1024 + 8 * lane + m; rb[m] = (i < n) ? x[s + i] : PADV; }
    }

    float mx = r[0];
    #pragma unroll
    for (int m = 1; m < 16; ++m) mx = fmaxf(mx, r[m]);
    if (med) {
        #pragma unroll
        for (int m = 0; m < 8; ++m) mx = fmaxf(mx, rb[m]);
    }
    #pragma unroll
    for (int o = 32; o; o >>= 1) mx = fmaxf(mx, __shfl_xor(mx, o, 64));
    if (lane == 0) mx_out[b] = mx;

    #pragma unroll
    for (int m = 0; m < 16; ++m) r[m] = r[m] - mx;
    if (med) {
        #pragma unroll
        for (int m = 0; m < 8; ++m) rb[m] = rb[m] - mx;
    }

    wsort1024(r, lane);

    if (med) {
        const int gib = 8 * lane;
        sort8(rb, gib);
        bmerge<16>(rb, gib); bmerge<32>(rb, gib); bmerge<64>(rb, gib);
        bmerge<128>(rb, gib); bmerge<256>(rb, gib); bmerge<512>(rb, gib);

        #pragma unroll
        for (int m = 0; m < 16; ++m) W[esw(16 * lane + m)] = r[m];
        #pragma unroll
        for (int m = 0; m < 8; ++m)  W[esw(1024 + 8 * lane + m)] = rb[m];

        float mg[24];
        const int d0 = 24 * lane;
        int cnt = 0;
        if (d0 < n) {
            int lo = (d0 > nb) ? d0 - nb : 0;
            int hi = (d0 < 1024) ? d0 : 1024;
            while (lo < hi) {
                const int a = (lo + hi) >> 1;
                if (W[esw(a)] >= W[esw(1024 + d0 - a - 1)]) lo = a + 1; else hi = a;
            }
            int i = lo, j = d0 - lo;
            cnt = (d0 + 24 < n) ? 24 : (n - d0);
            #pragma unroll
            for (int kk = 0; kk < 24; ++kk) {
                if (kk < cnt) {
                    const bool tA = (j >= nb) || (i < 1024 && W[esw(i)] >= W[esw(1024 + j)]);
                    if (tA) { mg[kk] = W[esw(i)]; ++i; }
                    else    { mg[kk] = W[esw(1024 + j)]; ++j; }
                }
            }
        }
        for (int kk = 0; kk < cnt; ++kk) W[esw(d0 + kk)] = mg[kk];
    } else {
        #pragma unroll
        for (int m = 0; m < 16; ++m) W[esw(16 * lane + m)] = r[m];
    }

    for (int i = lane; i < n; i += 64) S[s + i] = W[esw(i)];

    const int q0 = (s + 15) >> 4, q1 = e >> 4;
    for (int rr = lane; rr < q1 - q0; rr += 64) {
        const int lb = ((q0 + rr) << 4) - s;
        float v[16];
        #pragma unroll
        for (int ii = 0; ii < 16; ++ii) v[ii] = W[esw(lb + ii)];
        float a = 0.0f;
        #pragma unroll
        for (int ii = 0; ii < 16; ++ii) a = a + v[ii];
        L1[q0 + rr] = a;
    }
}

// -------- kTAIL: border -> L2/L3 -> pyramid+C1 -> base -> tau+out --------
__device__ __forceinline__ void gbar(int* ctr) {
    __syncthreads();
    if (threadIdx.x == 0) {
        __threadfence();
        atomicAdd(ctr, 1);
        while (__hip_atomic_load(ctr, __ATOMIC_RELAXED, __HIP_MEMORY_SCOPE_AGENT) < NTB)
            __builtin_amdgcn_s_sleep(8);
        __threadfence();
    }
    __syncthreads();
}

__global__ __launch_bounds__(256) void kTAIL(
    const float* __restrict__ x, const float* __restrict__ S,
    const int* __restrict__ starts, const int* __restrict__ batch,
    float* __restrict__ L1, float* __restrict__ L2, float* __restrict__ L3g,
    float* __restrict__ C1, const float* __restrict__ mx,
    float* __restrict__ baseA, float* __restrict__ rowP,
    float* __restrict__ out, int* __restrict__ ctrs)
{
    __shared__ float l3[L3N], c3[L3N], l4[128], c4[128], l5[8], c5[8];
    __shared__ float l2s[32], c2s[32], stau[1];
    const int blk = blockIdx.x, tid = threadIdx.x;

    // phase 0: border L1 rows (segment starts not 16-aligned)
    if (tid < SEGB) {
        const int b = blk * SEGB + tid;
        const int s = starts[b];
        if (s & 15) {
            const int q = s >> 4;
            const float* p = S + ((size_t)q << 4);
            float a = 0.0f;
            #pragma unroll
            for (int i = 0; i < 16; ++i) a = a + p[i];
            L1[q] = a;
        }
    }
    gbar(ctrs + 0);

    // phase 1: L2 rows (32/block) + L3 rows (2/block)
    if (tid < 32) {
        const int q2 = blk * 32 + tid;
        const float4* p = (const float4*)(L1 + ((size_t)q2 << 4));
        float a = 0.0f;
        #pragma unroll
        for (int v = 0; v < 4; ++v) {
            const float4 f = p[v];
            a = a + f.x; a = a + f.y; a = a + f.z; a = a + f.w;
        }
        L2[q2] = a;
        l2s[tid] = a;
    }
    __syncthreads();
    if (tid < 2) {
        float a = 0.0f;
        #pragma unroll
        for (int i = 0; i < 16; ++i) a = a + l2s[(tid << 4) + i];
        L3g[blk * 2 + tid] = a;
    }
    gbar(ctrs + 1);

    // phase 2: redundant in-LDS pyramid (L3->C3), C2 slice, C1 rows (32/block)
    for (int q = tid; q < L3N; q += 256) l3[q] = L3g[q];
    __syncthreads();
    if (tid < 128) {
        float a = 0.0f;
        for (int i = 0; i < 16; ++i) a = a + l3[tid * 16 + i];
        l4[tid] = a;
    }
    __syncthreads();
    if (tid < 8) {
        float a = 0.0f;
        for (int i = 0; i < 16; ++i) a = a + l4[tid * 16 + i];
        l5[tid] = a;
    }
    __syncthreads();
    if (tid == 0) {
        float a = 0.0f;
        for (int i = 0; i < 8; ++i) { a = a + l5[i]; c5[i] = a; }
    }
    __syncthreads();
    if (tid < 8) {
        const float pre = tid ? c5[tid - 1] : 0.0f;
        float a = 0.0f;
        for (int i = 0; i < 16; ++i) { a = a + l4[tid * 16 + i]; c4[tid * 16 + i] = tid ? (a + pre) : a; }
    }
    __syncthreads();
    if (tid < 128) {
        const float pre = tid ? c4[tid - 1] : 0.0f;
        float a = 0.0f;
        for (int i = 0; i < 16; ++i) { a = a + l3[tid * 16 + i]; c3[tid * 16 + i] = tid ? (a + pre) : a; }
    }
    __syncthreads();
    if (tid < 2) {
        const int q2r = blk * 2 + tid;
        const float pre = q2r ? c3[q2r - 1] : 0.0f;
        const float* p = L2 + ((size_t)q2r << 4);
        float a = 0.0f;
        #pragma unroll
        for (int i = 0; i < 16; ++i) { a = a + p[i]; c2s[(tid << 4) + i] = q2r ? (a + pre) : a; }
    }
    __syncthreads();
    if (tid < 32) {
        const int p1 = blk * 32 + 1 + tid;
        if (p1 < L2N) {
            const float pre = c2s[tid];
            const float* pL = L1 + ((size_t)p1 << 4);
            float a = 0.0f;
            #pragma unroll
            for (int i = 0; i < 16; ++i) { a = a + pL[i]; C1[((size_t)p1 << 4) + i] = a + pre; }
        }
    }
    if (blk == 0 && tid == 0) {
        float a = 0.0f;
        #pragma unroll
        for (int i = 0; i < 16; ++i) { a = a + L1[i]; C1[i] = a; }
    }
    gbar(ctrs + 2);

    // phase 3: per-segment base = c(s-1) and boundary-row partial prefix
    if (tid < SEGB) {
        const int b = blk * SEGB + tid;
        const int s = starts[b];
        float P = 0.0f, base = 0.0f;
        if (s > 0) {
            const int j = s - 1;
            const int q = j >> 4;
            const float* p = S + ((size_t)q << 4);
            float a = 0.0f;
            for (int i = 0; i <= (j & 15); ++i) a = a + p[i];
            if (s & 15) P = a;
            base = q ? (a + C1[q - 1]) : a;
        }
        baseA[b] = base;
        rowP[b] = P;
    }
    gbar(ctrs + 3);

    // phase 4: tau + output, SEGB segments sequential per block
    for (int si = 0; si < SEGB; ++si) {
        const int b = blk * SEGB + si;
        const int s = starts[b], e = starts[b + 1];
        const int n = e - s;
        if (n <= 0) continue;                      // uniform across block

        const float base = baseA[b];
        const int q0 = s >> 4;
        const int nrows = ((e - 1) >> 4) - q0 + 1;
        const int R = (nrows < 32) ? nrows : 32;   // exact-margin cap (R12-verified)

        int cnt = 0;
        if (tid < R) {
            const int q = q0 + tid;
            const float pre = q ? C1[q - 1] : 0.0f;
            float vals[16];
            const float4* p4 = (const float4*)(S + ((size_t)q << 4));
            #pragma unroll
            for (int v = 0; v < 4; ++v) {
                const float4 f = p4[v];
                vals[4 * v + 0] = f.x; vals[4 * v + 1] = f.y;
                vals[4 * v + 2] = f.z; vals[4 * v + 3] = f.w;
            }
            float a = (tid == 0) ? rowP[b] : 0.0f;
            const int i0 = (tid == 0) ? (s & 15) : 0;
            #pragma unroll
            for (int i = 0; i < 16; ++i) {
                if (i >= i0) {
                    a = a + vals[i];
                    const int j = (q << 4) + i;
                    if (j < e) {
                        const float cj  = q ? (a + pre) : a;
                        const float seg = (cj - base) - 1.0f;
                        const float lhs = (float)(j - s + 1) * vals[i];
                        if (lhs > seg) cnt++;
                    }
                }
            }
        }
        if (tid < 64) {
            #pragma unroll
            for (int o = 16; o; o >>= 1) cnt += __shfl_xor(cnt, o, 64);
        }
        if (tid == 0) {
            const int supp = cnt;
            float t;
            if (supp > 0) {
                const int idx = s + supp - 1;
                const int qi = idx >> 4;
                const float* p = S + ((size_t)qi << 4);
                float a = (qi == q0) ? rowP[b] : 0.0f;
                const int i0 = (qi == q0) ? (s & 15) : 0;
                for (int i = i0; i <= (idx & 15); ++i) a = a + p[i];
                const float ci = qi ? (a + C1[qi - 1]) : a;
                t = ((ci - base) - 1.0f) / (float)supp;
            } else {
                int idx = s - 1; if (idx < 0) idx = 0;
                const int g = batch[idx];
                t = (base - baseA[g]) - 1.0f;
            }
            stau[0] = t;
        }
        __syncthreads();
        const float tb = stau[0];
        const float mxb = mx[b];
        for (int i = s + tid; i < e; i += 256) {
            float v = x[i] - mxb;
            v = v - tb;
            out[i] = v > 0.0f ? v : 0.0f;
        }
        __syncthreads();                           // protect stau for next segment
    }
}

// ---------------- fallback (ws/shape mismatch): plain sparsemax + sentinel ----------------
__global__ void fb_sparsemax(const float* x, const int* batch, float* out, int n_total)
{
    __shared__ float sred[FBB];
    __shared__ int   sredi[FBB];
    __shared__ int   sb2[2];
    const int tid = threadIdx.x;
    const int b = blockIdx.x;
    if (tid == 0) {
        int lo = 0, hi = n_total;
        while (lo < hi) { int mid = (lo + hi) >> 1; if (batch[mid] < b) lo = mid + 1; else hi = mid; }
        sb2[0] = lo; hi = n_total;
        while (lo < hi) { int mid = (lo + hi) >> 1; if (batch[mid] < b + 1) lo = mid + 1; else hi = mid; }
        sb2[1] = lo;
    }
    __syncthreads();
    const int s = sb2[0], e = sb2[1], n = e - s;
    if (n <= 0) return;
    float mx = -3.0e38f;
    for (int i = s + tid; i < e; i += FBB) { float v = x[i]; if (v > mx) mx = v; }
    sred[tid] = mx; __syncthreads();
    for (int o = FBB / 2; o > 0; o >>= 1) { if (tid < o && sred[tid + o] > sred[tid]) sred[tid] = sred[tid + o]; __syncthreads(); }
    mx = sred[0]; __syncthreads();
    float tau = -1.0f; int prev = -1;
    for (int it = 0; it < 64; ++it) {
        float sum = 0.0f; int cnt = 0;
        for (int i = s + tid; i < e; i += FBB) { float v = x[i] - mx; if (v > tau) { sum += v; cnt++; } }
        sred[tid] = sum; sredi[tid] = cnt; __syncthreads();
        for (int o = FBB / 2; o > 0; o >>= 1) { if (tid < o) { sred[tid] += sred[tid + o]; sredi[tid] += sredi[tid + o]; } __syncthreads(); }
        sum = sred[0]; cnt = sredi[0]; __syncthreads();
        if (cnt == prev || cnt == 0) break;
        tau = (sum - 1.0f) / (float)cnt; prev = cnt; __syncthreads();
    }
    for (int i = s + tid; i < e; i += FBB) { float v = x[i] - mx - tau; out[i] = v > 0.0f ? v : 0.0f; }
}
__global__ void fb_sentinel(float* out) { if (threadIdx.x == 0 && blockIdx.x == 0) out[0] = 20000.0f; }

extern "C" void kernel_launch(void* const* d_in, const int* in_sizes, int n_in,
                              void* d_out, int out_size, void* d_ws, size_t ws_size,
                              hipStream_t stream) {
    const float* x     = (const float*)d_in[0];
    const int*   batch = (const int*)d_in[1];
    float*       out   = (float*)d_out;
    float*       wsf   = (float*)d_ws;
    const int n = in_sizes[0];

    // ws floats: ctrs 8 + starts 8200 + mx 8192 + baseA 8192 + rowP 8192 + L1 + L2 + L3 + C1
    const size_t need = (size_t)8 + 8200 + 8192 * 3 + L1N + L2N + L3N + L1N;
    if (n != NTOT || ws_size < need * sizeof(float)) {
        fb_sparsemax<<<NSEG, FBB, 0, stream>>>(x, batch, out, n);
        fb_sentinel<<<1, 64, 0, stream>>>(out);
        return;
    }
    int*   ctrs   = (int*)wsf;
    int*   starts = (int*)(wsf + 8);
    float* mx     = wsf + 8208;
    float* baseA  = mx + 8192;
    float* rowP   = baseA + 8192;
    float* L1 = rowP + 8192;
    float* L2 = L1 + L1N;
    float* L3 = L2 + L2N;
    float* C1 = L3 + L3N;
    float* S  = out;   // sorted xs lives in d_out until kTAIL phase 4 overwrites

    k1_bounds<<<(n + 255) / 256, 256, 0, stream>>>(batch, starts, ctrs, n);
    k2w<<<NSEG / 4, 256, 0, stream>>>(x, starts, mx, S, L1);
    kTAIL<<<NTB, 256, 0, stream>>>(x, S, starts, batch, L1, L2, L3, C1, mx, baseA, rowP, out, ctrs);
}

// Round 15
// 213.802 us; speedup vs baseline: 2.7897x; 2.7897x over previous
//
#include <hip/hip_runtime.h>

// Bit-exact emulation of segmented sparsemax with cumsum lowered like XLA's
// ReduceWindowRewriter (base 16). GREEN since R7 (absmax 0.0).
// R15: revert R14's spin-barrier kernel (437us, VALUBusy 1.8% -- device spin
// barriers are poison on 8-XCD MI355X). Structure = R13 minus launches:
//   kM1 = border-fix + L1->L2->L3 fused (per-block binary search, no cross dep)
//   big-ws path: S in workspace -> kCF = k_base+kC fused (no S/out aliasing)
// All scan arithmetic keeps the exact association order of the verified chain.

#define NSEG   8192
#define NTOT   8388608   // 2^23
#define L1N    524288    // 2^19
#define L2N    32768     // 2^15
#define L3N    2048
#define PADV   (-3.0e38f)
#define WREG   1552      // per-wave LDS floats (1536 + 16 pad)
#define FBB    256

__device__ __forceinline__ int esw(const int e) {
    return (e & ~15) | ((e + (e >> 4)) & 15);
}

__device__ __forceinline__ void cs(float& a, float& b, const bool up) {
    const float lo = fminf(a, b), hi = fmaxf(a, b);
    a = up ? hi : lo;
    b = up ? lo : hi;
}

// ---- 8-reg (512) wave sort (verified since R9) ----
__device__ __forceinline__ void sort8(float r[8], const int gib) {
    cs(r[0], r[1], true);  cs(r[2], r[3], false); cs(r[4], r[5], true);  cs(r[6], r[7], false);
    cs(r[0], r[2], true);  cs(r[1], r[3], true);  cs(r[4], r[6], false); cs(r[5], r[7], false);
    cs(r[0], r[1], true);  cs(r[2], r[3], true);  cs(r[4], r[5], false); cs(r[6], r[7], false);
    const bool u8 = ((gib & 8) == 0);
    cs(r[0], r[4], u8); cs(r[1], r[5], u8); cs(r[2], r[6], u8); cs(r[3], r[7], u8);
    cs(r[0], r[2], u8); cs(r[1], r[3], u8); cs(r[4], r[6], u8); cs(r[5], r[7], u8);
    cs(r[0], r[1], u8); cs(r[2], r[3], u8); cs(r[4], r[5], u8); cs(r[6], r[7], u8);
}

template<int K>
__device__ __forceinline__ void bmerge(float r[8], const int gib) {
    const bool up = ((gib & K) == 0);
    #pragma unroll
    for (int j = K >> 1; j >= 8; j >>= 1) {
        const bool tkm = (up == ((gib & j) == 0));
        const int tm = j >> 3;
        #pragma unroll
        for (int m = 0; m < 8; ++m) {
            const float p = __shfl_xor(r[m], tm, 64);
            r[m] = tkm ? fmaxf(r[m], p) : fminf(r[m], p);
        }
    }
    #pragma unroll
    for (int j = 4; j >= 1; j >>= 1)
        #pragma unroll
        for (int m = 0; m < 8; ++m)
            if ((m & j) == 0) cs(r[m], r[m | j], up);
}

// ---- 16-reg (1024) wave sort ----
template<int K, int J>
__device__ __forceinline__ void cepm(float r[16]) {
    #pragma unroll
    for (int m = 0; m < 16; ++m)
        if ((m & J) == 0) { const bool up = ((m & K) == 0); cs(r[m], r[m | J], up); }
}
template<int J>
__device__ __forceinline__ void cep(float r[16], const bool up) {
    #pragma unroll
    for (int m = 0; m < 16; ++m)
        if ((m & J) == 0) cs(r[m], r[m | J], up);
}
template<int KD>
__device__ __forceinline__ void kphase16(float r[16], const int l) {
    const bool up = ((l & (KD >> 4)) == 0);
    #pragma unroll
    for (int tm = KD >> 5; tm >= 1; tm >>= 1) {
        const bool tkm = (up == ((l & tm) == 0));
        #pragma unroll
        for (int m = 0; m < 16; ++m) {
            const float p = __shfl_xor(r[m], tm, 64);
            r[m] = tkm ? fmaxf(r[m], p) : fminf(r[m], p);
        }
    }
    cep<8>(r, up); cep<4>(r, up); cep<2>(r, up); cep<1>(r, up);
}
__device__ __forceinline__ void wsort1024(float r[16], const int l) {
    cepm<2, 1>(r);
    cepm<4, 2>(r); cepm<4, 1>(r);
    cepm<8, 4>(r); cepm<8, 2>(r); cepm<8, 1>(r);
    kphase16<16>(r, l);  kphase16<32>(r, l);  kphase16<64>(r, l);
    kphase16<128>(r, l); kphase16<256>(r, l); kphase16<512>(r, l);
    kphase16<1024>(r, l);
}

__global__ void k1_bounds(const int* __restrict__ batch, int* __restrict__ starts, const int n)
{
    const int i = blockIdx.x * blockDim.x + threadIdx.x;
    if (i >= n) return;
    const int bi = batch[i];
    if (i == 0) { for (int b = 0; b <= bi; ++b) starts[b] = 0; }
    else {
        const int bp = batch[i - 1];
        for (int b = bp + 1; b <= bi; ++b) starts[b] = i;
    }
    if (i == n - 1) { for (int b = bi + 1; b <= NSEG; ++b) starts[b] = n; }
}

// -------- k2w: one WAVE per segment (unchanged from R13, S pointer generic) --------
__global__ __launch_bounds__(256) void k2w(
    const float* __restrict__ x, const int* __restrict__ starts,
    float* __restrict__ mx_out, float* __restrict__ S, float* __restrict__ L1)
{
    __shared__ __align__(16) float Wall[4 * WREG];
    const int tid  = threadIdx.x;
    const int lane = tid & 63;
    const int wid  = tid >> 6;
    float* W = Wall + wid * WREG;

    const int b = blockIdx.x * 4 + wid;
    const int s = starts[b], e = starts[b + 1];
    const int n = e - s;
    if (n <= 0) { if (lane == 0) mx_out[b] = 0.0f; return; }

    const bool med = (n > 1024);
    const int  nb  = n - 1024;

    float r[16], rb[8];
    #pragma unroll
    for (int m = 0; m < 16; ++m) { const int i = 16 * lane + m; r[m] = (i < n) ? x[s + i] : PADV; }
    if (med) {
        #pragma unroll
        for (int m = 0; m < 8; ++m) { const int i = 1024 + 8 * lane + m; rb[m] = (i < n) ? x[s + i] : PADV; }
    }

    float mx = r[0];
    #pragma unroll
    for (int m = 1; m < 16; ++m) mx = fmaxf(mx, r[m]);
    if (med) {
        #pragma unroll
        for (int m = 0; m < 8; ++m) mx = fmaxf(mx, rb[m]);
    }
    #pragma unroll
    for (int o = 32; o; o >>= 1) mx = fmaxf(mx, __shfl_xor(mx, o, 64));
    if (lane == 0) mx_out[b] = mx;

    #pragma unroll
    for (int m = 0; m < 16; ++m) r[m] = r[m] - mx;
    if (med) {
        #pragma unroll
        for (int m = 0; m < 8; ++m) rb[m] = rb[m] - mx;
    }

    wsort1024(r, lane);

    if (med) {
        const int gib = 8 * lane;
        sort8(rb, gib);
        bmerge<16>(rb, gib); bmerge<32>(rb, gib); bmerge<64>(rb, gib);
        bmerge<128>(rb, gib); bmerge<256>(rb, gib); bmerge<512>(rb, gib);

        #pragma unroll
        for (int m = 0; m < 16; ++m) W[esw(16 * lane + m)] = r[m];
        #pragma unroll
        for (int m = 0; m < 8; ++m)  W[esw(1024 + 8 * lane + m)] = rb[m];

        float mg[24];
        const int d0 = 24 * lane;
        int cnt = 0;
        if (d0 < n) {
            int lo = (d0 > nb) ? d0 - nb : 0;
            int hi = (d0 < 1024) ? d0 : 1024;
            while (lo < hi) {
                const int a = (lo + hi) >> 1;
                if (W[esw(a)] >= W[esw(1024 + d0 - a - 1)]) lo = a + 1; else hi = a;
            }
            int i = lo, j = d0 - lo;
            cnt = (d0 + 24 < n) ? 24 : (n - d0);
            #pragma unroll
            for (int kk = 0; kk < 24; ++kk) {
                if (kk < cnt) {
                    const bool tA = (j >= nb) || (i < 1024 && W[esw(i)] >= W[esw(1024 + j)]);
                    if (tA) { mg[kk] = W[esw(i)]; ++i; }
                    else    { mg[kk] = W[esw(1024 + j)]; ++j; }
                }
            }
        }
        for (int kk = 0; kk < cnt; ++kk) W[esw(d0 + kk)] = mg[kk];
    } else {
        #pragma unroll
        for (int m = 0; m < 16; ++m) W[esw(16 * lane + m)] = r[m];
    }

    for (int i = lane; i < n; i += 64) S[s + i] = W[esw(i)];

    const int q0 = (s + 15) >> 4, q1 = e >> 4;
    for (int rr = lane; rr < q1 - q0; rr += 64) {
        const int lb = ((q0 + rr) << 4) - s;
        float v[16];
        #pragma unroll
        for (int ii = 0; ii < 16; ++ii) v[ii] = W[esw(lb + ii)];
        float a = 0.0f;
        #pragma unroll
        for (int ii = 0; ii < 16; ++ii) a = a + v[ii];
        L1[q0 + rr] = a;
    }
}

// -------- kM1: border-row fix + L1 -> L2 -> L3 (128 blocks, no cross-block dep) --------
__global__ __launch_bounds__(256) void kM1(
    const float* __restrict__ S, const int* __restrict__ starts,
    float* __restrict__ L1, float* __restrict__ L2, float* __restrict__ L3)
{
    __shared__ float l2s[256];
    __shared__ int sbr[2];
    const int k = blockIdx.x, tid = threadIdx.x;

    // segments with starts in [65536k, 65536(k+1)) have border rows in this
    // block's L1 window [4096k, 4096(k+1))
    if (tid < 2) {
        const int target = 65536 * (k + tid);
        int lo = 0, hi = NSEG;
        while (lo < hi) { const int mid = (lo + hi) >> 1; if (starts[mid] < target) lo = mid + 1; else hi = mid; }
        sbr[tid] = lo;
    }
    __syncthreads();
    for (int b = sbr[0] + tid; b < sbr[1]; b += 256) {
        const int s = starts[b];
        if (s & 15) {
            const int q = s >> 4;
            const float* p = S + ((size_t)q << 4);
            float a = 0.0f;
            #pragma unroll
            for (int i = 0; i < 16; ++i) a = a + p[i];
            L1[q] = a;
        }
    }
    __syncthreads();   // border rows visible to this block's reads below

    const int q2 = (k << 8) + tid;
    {
        const float* p = L1 + ((size_t)q2 << 4);
        float a = 0.0f;
        #pragma unroll
        for (int i = 0; i < 16; ++i) a = a + p[i];   // rows may mix scalar/vec writes; scalar reads safe
        L2[q2] = a;
        l2s[tid] = a;
    }
    __syncthreads();
    if (tid < 16) {
        float a = 0.0f;
        #pragma unroll
        for (int i = 0; i < 16; ++i) a = a + l2s[(tid << 4) + i];
        L3[(k << 4) + tid] = a;
    }
}

// -------- kB: redundant in-LDS pyramid (L3->C3), C2 slice, C1 chunk (unchanged) --------
__global__ __launch_bounds__(256) void kB(const float* __restrict__ L1,
                                          const float* __restrict__ L2,
                                          const float* __restrict__ L3g,
                                          float* __restrict__ C1)
{
    __shared__ float l3[L3N], c3[L3N], l4[128], c4[128], l5[8], c5[8], c2s[256];
    const int k = blockIdx.x, tid = threadIdx.x;

    for (int q = tid; q < L3N; q += 256) l3[q] = L3g[q];
    __syncthreads();
    if (tid < 128) {
        float a = 0.0f;
        for (int i = 0; i < 16; ++i) a = a + l3[tid * 16 + i];
        l4[tid] = a;
    }
    __syncthreads();
    if (tid < 8) {
        float a = 0.0f;
        for (int i = 0; i < 16; ++i) a = a + l4[tid * 16 + i];
        l5[tid] = a;
    }
    __syncthreads();
    if (tid == 0) {
        float a = 0.0f;
        for (int i = 0; i < 8; ++i) { a = a + l5[i]; c5[i] = a; }
    }
    __syncthreads();
    if (tid < 8) {
        const float pre = tid ? c5[tid - 1] : 0.0f;
        float a = 0.0f;
        for (int i = 0; i < 16; ++i) { a = a + l4[tid * 16 + i]; c4[tid * 16 + i] = tid ? (a + pre) : a; }
    }
    __syncthreads();
    if (tid < 128) {
        const float pre = tid ? c4[tid - 1] : 0.0f;
        float a = 0.0f;
        for (int i = 0; i < 16; ++i) { a = a + l3[tid * 16 + i]; c3[tid * 16 + i] = tid ? (a + pre) : a; }
    }
    __syncthreads();
    if (tid < 16) {
        const int q2r = (k << 4) + tid;
        const float pre = q2r ? c3[q2r - 1] : 0.0f;
        const float* p = L2 + ((size_t)q2r << 4);
        float a = 0.0f;
        #pragma unroll
        for (int i = 0; i < 16; ++i) { a = a + p[i]; c2s[(tid << 4) + i] = q2r ? (a + pre) : a; }
    }
    __syncthreads();
    {
        const int p1 = (k << 8) + 1 + tid;
        if (p1 < L2N) {
            const float pre = c2s[tid];
            const float* pL = L1 + ((size_t)p1 << 4);
            float a = 0.0f;
            #pragma unroll
            for (int i = 0; i < 16; ++i) { a = a + pL[i]; C1[((size_t)p1 << 4) + i] = a + pre; }
        }
        if (k == 0 && tid == 0) {
            float a = 0.0f;
            #pragma unroll
            for (int i = 0; i < 16; ++i) { a = a + L1[i]; C1[i] = a; }
        }
    }
}

// c(j) helper: full-row fold + C1 prefix (exact chain)
__device__ __forceinline__ float c_row(const int j, const float* __restrict__ S,
                                       const float* __restrict__ C1)
{
    const int q = j >> 4;
    const float* p = S + ((size_t)q << 4);
    float a = 0.0f;
    for (int i = 0; i <= (j & 15); ++i) a = a + p[i];
    return q ? (a + C1[q - 1]) : a;
}

// -------- kCF (big-ws): base + tau + out, self-contained (S intact in ws) --------
__global__ __launch_bounds__(128) void kCF(
    const float* __restrict__ x, const float* __restrict__ S, const float* __restrict__ C1,
    const int* __restrict__ starts, const int* __restrict__ batch,
    const float* __restrict__ mx, float* __restrict__ out)
{
    __shared__ float stau[1], sbase[1];
    __shared__ int   scnt[2];

    const int b = blockIdx.x, tid = threadIdx.x;
    const int s = starts[b], e = starts[b + 1];
    const int n = e - s;
    if (n <= 0) return;

    if (tid == 0) sbase[0] = (s > 0) ? c_row(s - 1, S, C1) : 0.0f;
    __syncthreads();
    const float base = sbase[0];

    const int q0 = s >> 4;
    const int nrows = ((e - 1) >> 4) - q0 + 1;
    const int R = (nrows < 32) ? nrows : 32;   // exact-margin cap (R12-verified)

    int cnt = 0;
    for (int rr = tid; rr < R; rr += 128) {
        const int q = q0 + rr;
        const float pre = q ? C1[q - 1] : 0.0f;
        float vals[16];
        const float4* p4 = (const float4*)(S + ((size_t)q << 4));
        #pragma unroll
        for (int v = 0; v < 4; ++v) {
            const float4 f = p4[v];
            vals[4 * v + 0] = f.x; vals[4 * v + 1] = f.y;
            vals[4 * v + 2] = f.z; vals[4 * v + 3] = f.w;
        }
        float a = 0.0f;
        #pragma unroll
        for (int i = 0; i < 16; ++i) {
            a = a + vals[i];                         // full-row fold (bit-exact)
            const int j = (q << 4) + i;
            if (j >= s && j < e) {
                const float cj  = q ? (a + pre) : a;
                const float seg = (cj - base) - 1.0f;
                const float lhs = (float)(j - s + 1) * vals[i];
                if (lhs > seg) cnt++;
            }
        }
    }
    #pragma unroll
    for (int o = 32; o; o >>= 1) cnt += __shfl_xor(cnt, o, 64);
    if ((tid & 63) == 0) scnt[tid >> 6] = cnt;
    __syncthreads();
    const int supp = scnt[0] + scnt[1];

    if (tid == 0) {
        float t;
        if (supp > 0) {
            const int idx = s + supp - 1;
            const float ci = c_row(idx, S, C1);
            t = ((ci - base) - 1.0f) / (float)supp;
        } else {
            const int g  = batch[s - 1];             // leak: prev segment (s>0 here)
            const int sg = starts[g];
            const float bg = (sg > 0) ? c_row(sg - 1, S, C1) : 0.0f;
            t = (base - bg) - 1.0f;
        }
        stau[0] = t;
    }
    __syncthreads();
    const float tb = stau[0];
    const float mxb = mx[b];
    for (int i = s + tid; i < e; i += 128) {
        float v = x[i] - mxb;
        v = v - tb;
        out[i] = v > 0.0f ? v : 0.0f;
    }
}

// -------- small-ws fallback pair: k_base + kC (R13-verified, S aliased with out) --------
__global__ void k_base(const float* __restrict__ S, const float* __restrict__ C1,
                       const int* __restrict__ starts,
                       float* __restrict__ baseA, float* __restrict__ rowP)
{
    const int b = blockIdx.x * blockDim.x + threadIdx.x;
    if (b >= NSEG) return;
    const int s = starts[b];
    float P = 0.0f, base = 0.0f;
    if (s > 0) {
        const int j = s - 1;
        const int q = j >> 4;
        const float* p = S + ((size_t)q << 4);
        float a = 0.0f;
        for (int i = 0; i <= (j & 15); ++i) a = a + p[i];
        if (s & 15) P = a;
        base = q ? (a + C1[q - 1]) : a;
    }
    baseA[b] = base;
    rowP[b] = P;
}

__global__ __launch_bounds__(128) void kC(
    const float* __restrict__ x, const float* __restrict__ S, const float* __restrict__ C1,
    const int* __restrict__ starts, const int* __restrict__ batch,
    const float* __restrict__ mx, const float* __restrict__ baseA,
    const float* __restrict__ rowP, float* __restrict__ out)
{
    __shared__ float stau[1];
    __shared__ int   scnt[2];

    const int b = blockIdx.x, tid = threadIdx.x;
    const int s = starts[b], e = starts[b + 1];
    const int n = e - s;
    if (n <= 0) return;

    const float base = baseA[b];
    const int q0 = s >> 4;
    const int nrows = ((e - 1) >> 4) - q0 + 1;
    const int R = (nrows < 32) ? nrows : 32;

    int cnt = 0;
    for (int rr = tid; rr < R; rr += 128) {
        const int q = q0 + rr;
        const float pre = q ? C1[q - 1] : 0.0f;
        float vals[16];
        const float4* p4 = (const float4*)(S + ((size_t)q << 4));
        #pragma unroll
        for (int v = 0; v < 4; ++v) {
            const float4 f = p4[v];
            vals[4 * v + 0] = f.x; vals[4 * v + 1] = f.y;
            vals[4 * v + 2] = f.z; vals[4 * v + 3] = f.w;
        }
        float a = (rr == 0) ? rowP[b] : 0.0f;
        const int i0 = (rr == 0) ? (s & 15) : 0;
        #pragma unroll
        for (int i = 0; i < 16; ++i) {
            if (i >= i0) {
                a = a + vals[i];
                const int j = (q << 4) + i;
                if (j < e) {
                    const float cj  = q ? (a + pre) : a;
                    const float seg = (cj - base) - 1.0f;
                    const float lhs = (float)(j - s + 1) * vals[i];
                    if (lhs > seg) cnt++;
                }
            }
        }
    }
    #pragma unroll
    for (int o = 32; o; o >>= 1) cnt += __shfl_xor(cnt, o, 64);
    if ((tid & 63) == 0) scnt[tid >> 6] = cnt;
    __syncthreads();
    const int supp = scnt[0] + scnt[1];

    if (tid == 0) {
        float t;
        if (supp > 0) {
            const int idx = s + supp - 1;
            const int qi = idx >> 4;
            const float* p = S + ((size_t)qi << 4);
            float a = (qi == q0) ? rowP[b] : 0.0f;
            const int i0 = (qi == q0) ? (s & 15) : 0;
            for (int i = i0; i <= (idx & 15); ++i) a = a + p[i];
            const float ci = qi ? (a + C1[qi - 1]) : a;
            t = ((ci - base) - 1.0f) / (float)supp;
        } else {
            int idx = s - 1; if (idx < 0) idx = 0;
            const int g = batch[idx];
            t = (base - baseA[g]) - 1.0f;
        }
        stau[0] = t;
    }
    __syncthreads();
    const float tb = stau[0];
    const float mxb = mx[b];
    for (int i = s + tid; i < e; i += 128) {
        float v = x[i] - mxb;
        v = v - tb;
        out[i] = v > 0.0f ? v : 0.0f;
    }
}

// ---------------- fallback (shape mismatch): plain sparsemax + sentinel ----------------
__global__ void fb_sparsemax(const float* x, const int* batch, float* out, int n_total)
{
    __shared__ float sred[FBB];
    __shared__ int   sredi[FBB];
    __shared__ int   sb2[2];
    const int tid = threadIdx.x;
    const int b = blockIdx.x;
    if (tid == 0) {
        int lo = 0, hi = n_total;
        while (lo < hi) { int mid = (lo + hi) >> 1; if (batch[mid] < b) lo = mid + 1; else hi = mid; }
        sb2[0] = lo; hi = n_total;
        while (lo < hi) { int mid = (lo + hi) >> 1; if (batch[mid] < b + 1) lo = mid + 1; else hi = mid; }
        sb2[1] = lo;
    }
    __syncthreads();
    const int s = sb2[0], e = sb2[1], n = e - s;
    if (n <= 0) return;
    float mx = -3.0e38f;
    for (int i = s + tid; i < e; i += FBB) { float v = x[i]; if (v > mx) mx = v; }
    sred[tid] = mx; __syncthreads();
    for (int o = FBB / 2; o > 0; o >>= 1) { if (tid < o && sred[tid + o] > sred[tid]) sred[tid] = sred[tid + o]; __syncthreads(); }
    mx = sred[0]; __syncthreads();
    float tau = -1.0f; int prev = -1;
    for (int it = 0; it < 64; ++it) {
        float sum = 0.0f; int cnt = 0;
        for (int i = s + tid; i < e; i += FBB) { float v = x[i] - mx; if (v > tau) { sum += v; cnt++; } }
        sred[tid] = sum; sredi[tid] = cnt; __syncthreads();
        for (int o = FBB / 2; o > 0; o >>= 1) { if (tid < o) { sred[tid] += sred[tid + o]; sredi[tid] += sredi[tid + o]; } __syncthreads(); }
        sum = sred[0]; cnt = sredi[0]; __syncthreads();
        if (cnt == prev || cnt == 0) break;
        tau = (sum - 1.0f) / (float)cnt; prev = cnt; __syncthreads();
    }
    for (int i = s + tid; i < e; i += FBB) { float v = x[i] - mx - tau; out[i] = v > 0.0f ? v : 0.0f; }
}
__global__ void fb_sentinel(float* out) { if (threadIdx.x == 0 && blockIdx.x == 0) out[0] = 20000.0f; }

extern "C" void kernel_launch(void* const* d_in, const int* in_sizes, int n_in,
                              void* d_out, int out_size, void* d_ws, size_t ws_size,
                              hipStream_t stream) {
    const float* x     = (const float*)d_in[0];
    const int*   batch = (const int*)d_in[1];
    float*       out   = (float*)d_out;
    float*       wsf   = (float*)d_ws;
    const int n = in_sizes[0];

    // shared prefix: starts 8448(int) + mx 8192 + L1 + L2 + L3 + C1
    const size_t base_f  = (size_t)8448 + 8192 + L1N + L2N + L3N + L1N;
    const size_t small_f = base_f + 8192 + 8192;          // + baseA + rowP
    const size_t big_f   = small_f + (size_t)NTOT;        // + S
    if (n != NTOT || ws_size < small_f * sizeof(float)) {
        fb_sparsemax<<<NSEG, FBB, 0, stream>>>(x, batch, out, n);
        fb_sentinel<<<1, 64, 0, stream>>>(out);
        return;
    }
    int*   starts = (int*)wsf;
    float* mx     = wsf + 8448;
    float* L1 = mx + 8192;
    float* L2 = L1 + L1N;
    float* L3 = L2 + L2N;
    float* C1 = L3 + L3N;
    float* baseA = C1 + L1N;
    float* rowP  = baseA + 8192;

    const bool big = (ws_size >= big_f * sizeof(float));
    float* S = big ? (rowP + 8192) : out;   // big: S in ws (no S/out aliasing)

    k1_bounds<<<(n + 255) / 256, 256, 0, stream>>>(batch, starts, n);
    k2w<<<NSEG / 4, 256, 0, stream>>>(x, starts, mx, S, L1);
    kM1<<<128, 256, 0, stream>>>(S, starts, L1, L2, L3);
    kB<<<128, 256, 0, stream>>>(L1, L2, L3, C1);
    if (big) {
        kCF<<<NSEG, 128, 0, stream>>>(x, S, C1, starts, batch, mx, out);
    } else {
        k_base<<<NSEG / 256, 256, 0, stream>>>(S, C1, starts, baseA, rowP);
        kC<<<NSEG, 128, 0, stream>>>(x, S, C1, starts, batch, mx, baseA, rowP, out);
    }
}